// Round 9
// baseline (234.394 us; speedup 1.0000x reference)
//
#include <hip/hip_runtime.h>

#define KK 32
#define HH 6
#define OO 31
#define EPS 1e-6f
#define PTS_BLK 256              // M=1: 256 threads, 1 pt/thread, full o per thread
#define V_DW (KK * 4 * HH * 8)   // 6144 dwords: V[k][oc(4)][h(6)][8]

typedef float f32x8 __attribute__((ext_vector_type(8)));
typedef float f32x4 __attribute__((ext_vector_type(4)));

// Sigma-folded, o-chunked, zero-padded W. 24.6 KB, rebuilt each launch by the
// prep kernel (inputs may be re-poisoned between iterations).
// Layout: V[k][oc][h][o8], o = oc*8 + o8, col o==31 zero-padded.
//   h=0: W0 - (W3+W5)/s2   h=1: -W1/s2 (x g*dy)   h=2: -W2/s2 (x g*dx)
//   h=3: W3/s4 (x g*dy^2)  h=4: W4/s4 (x g*dx*dy) h=5: W5/s4 (x g*dx^2)
__device__ __align__(256) float V_dev[V_DW];

__global__ void hermite_prep_kernel(const float* __restrict__ W,
                                    const float* __restrict__ sigmas)
{
    int j = blockIdx.x * 256 + threadIdx.x;
    if (j >= V_DW) return;
    int k  = j / 192;
    int r  = j - k * 192;
    int oc = r / 48;
    int r2 = r - oc * 48;
    int h  = r2 >> 3;
    int o  = oc * 8 + (r2 & 7);
    float s  = sigmas[k];
    float s2 = s * s;
    float i2 = 1.0f / (s2 + EPS);
    float i4 = 1.0f / (s2 * s2 + EPS);
    float v = 0.0f;
    if (o < OO) {
        const float* Wk = W + k * (HH * OO);
        float w = Wk[h * OO + o];
        if (h == 0)      v = w - i2 * (Wk[3 * OO + o] + Wk[5 * OO + o]);
        else if (h <= 2) v = -i2 * w;
        else             v = i4 * w;
    }
    V_dev[j] = v;
}

// DCHUNK8: one (k, 16-output) half -- 96 wave-uniform V dwords in flight
// under ONE lgkmcnt(0), as 12x s_load_dwordx8 (x8 tuples: loose alignment,
// many legal placements -- avoids R8's x16-tuple allocator saturation that
// correlated with replay corruption). Same cache lines touched (6x64B).
// Latency model (validated R2/R3/R6): per wait-group time = L(~600) + 2D cyc;
// D=96 -> 2 groups/k -> duty 4*384/(2*(600+192)) = 97% (VALU-saturated).
// Loads + wait in ONE asm: consumers data-depend on the asm outputs (no
// hoist hazard); SMEM returns may be OOO so only lgkmcnt(0) is safe.
// sched_barrier(0) pins any residual reordering across the asm boundary.
#define DCHUNK8(PC, OCB)                                                   \
    {                                                                      \
        f32x8 t0, t1, t2, t3, t4, t5, t6, t7, t8, t9, ta, tb;              \
        asm volatile("s_load_dwordx8 %0, %12, 0x0\n\t"                     \
                     "s_load_dwordx8 %1, %12, 0x20\n\t"                    \
                     "s_load_dwordx8 %2, %12, 0x40\n\t"                    \
                     "s_load_dwordx8 %3, %12, 0x60\n\t"                    \
                     "s_load_dwordx8 %4, %12, 0x80\n\t"                    \
                     "s_load_dwordx8 %5, %12, 0xa0\n\t"                    \
                     "s_load_dwordx8 %6, %12, 0xc0\n\t"                    \
                     "s_load_dwordx8 %7, %12, 0xe0\n\t"                    \
                     "s_load_dwordx8 %8, %12, 0x100\n\t"                   \
                     "s_load_dwordx8 %9, %12, 0x120\n\t"                   \
                     "s_load_dwordx8 %10, %12, 0x140\n\t"                  \
                     "s_load_dwordx8 %11, %12, 0x160\n\t"                  \
                     "s_waitcnt lgkmcnt(0)"                                \
                     : "=&s"(t0), "=&s"(t1), "=&s"(t2), "=&s"(t3),         \
                       "=&s"(t4), "=&s"(t5), "=&s"(t6), "=&s"(t7),         \
                       "=&s"(t8), "=&s"(t9), "=&s"(ta), "=&s"(tb)          \
                     : "s"(PC));                                           \
        __builtin_amdgcn_sched_barrier(0);                                 \
        _Pragma("unroll")                                                  \
        for (int o = 0; o < 8; ++o) {                                      \
            float a = acc[(OCB) + o];                                      \
            a = fmaf(g,  t0[o], a);                                        \
            a = fmaf(d1, t1[o], a);                                        \
            a = fmaf(d2, t2[o], a);                                        \
            a = fmaf(d3, t3[o], a);                                        \
            a = fmaf(d4, t4[o], a);                                        \
            a = fmaf(d5, t5[o], a);                                        \
            acc[(OCB) + o] = a;                                            \
            float b = acc[(OCB) + 8 + o];                                  \
            b = fmaf(g,  t6[o], b);                                        \
            b = fmaf(d1, t7[o], b);                                        \
            b = fmaf(d2, t8[o], b);                                        \
            b = fmaf(d3, t9[o], b);                                        \
            b = fmaf(d4, ta[o], b);                                        \
            b = fmaf(d5, tb[o], b);                                        \
            acc[(OCB) + 8 + o] = b;                                        \
        }                                                                  \
    }

// 8 consecutive k's against one 64B cd sector already staged in c[16].
#define JBLOCK(VS, GOFF)                                                   \
    _Pragma("unroll")                                                      \
    for (int j = 0; j < 8; ++j) {                                          \
        float dx = c[2 * j], dy = c[2 * j + 1];                            \
        float g  = ga[(GOFF) + j];                                         \
        float d1 = g * dy, d2 = g * dx;                                    \
        float d3 = d1 * dy, d4 = d1 * dx, d5 = d2 * dx;                    \
        const float* pk = (VS) + j * 192;                                  \
        DCHUNK8(pk,      0)                                                \
        DCHUNK8(pk + 96, 16)                                               \
    }

__global__ __launch_bounds__(256, 4) void hermite_fused_kernel(
    const float* __restrict__ mlp,     // [P, OO]
    const float* __restrict__ cd,      // [P, KK, 2]
    const float* __restrict__ gw,      // [P, KK]
    float* __restrict__ out)           // [P, OO]
{
    __shared__ float smem[PTS_BLK * OO];   // 7936 dwords = 31744 B

    const int tid = threadIdx.x;
    const int p   = blockIdx.x * PTS_BLK + tid;
    const float4* __restrict__ cdv = (const float4*)(cd + (size_t)p * (KK * 2));
    const float4* __restrict__ gwv = (const float4*)(gw + (size_t)p * KK);

    float acc[32];
#pragma unroll
    for (int o = 0; o < 32; ++o) acc[o] = 0.0f;

    const float* __restrict__ Vb = V_dev;

    // 2 outer iterations x 16 k. gw staged 16 k at a time (4 float4 = one
    // full 64B sector/lane); cd staged 8 k at a time (4 float4 = one full
    // 64B sector/lane). All register arrays statically indexed.
#pragma unroll 1
    for (int kt2 = 0; kt2 < 2; ++kt2) {
        float ga[16];
#pragma unroll
        for (int i = 0; i < 4; ++i) {
            float4 t = gwv[kt2 * 4 + i];
            ga[4 * i + 0] = t.x; ga[4 * i + 1] = t.y;
            ga[4 * i + 2] = t.z; ga[4 * i + 3] = t.w;
        }

        float c[16];
#pragma unroll
        for (int i = 0; i < 4; ++i) {
            float4 t = cdv[kt2 * 8 + i];
            c[4 * i + 0] = t.x; c[4 * i + 1] = t.y;
            c[4 * i + 2] = t.z; c[4 * i + 3] = t.w;
        }
        const float* Vs0 = Vb + (size_t)kt2 * (16 * 192);
        JBLOCK(Vs0, 0)

#pragma unroll
        for (int i = 0; i < 4; ++i) {
            float4 t = cdv[kt2 * 8 + 4 + i];
            c[4 * i + 0] = t.x; c[4 * i + 1] = t.y;
            c[4 * i + 2] = t.z; c[4 * i + 3] = t.w;
        }
        const float* Vs1 = Vs0 + 8 * 192;
        JBLOCK(Vs1, 8)
    }

    // Epilogue: transpose through LDS for coalesced float4 mlp*mix -> out.
    // Write banks (31*tid + o) mod 32 = (o - tid) mod 32: conflict-free.
#pragma unroll
    for (int o = 0; o < OO; ++o) smem[tid * OO + o] = acc[o];
    __syncthreads();

    {
        const size_t blk_dw = (size_t)blockIdx.x * (PTS_BLK * OO);
        const f32x4* __restrict__ mlpv = (const f32x4*)(mlp + blk_dw);
        f32x4* __restrict__ outv = (f32x4*)(out + blk_dw);
        const f32x4* mixv = (const f32x4*)smem;
#pragma unroll 2
        for (int j = tid; j < (PTS_BLK * OO) / 4; j += 256) {
            f32x4 m = __builtin_nontemporal_load(&mlpv[j]);
            f32x4 x = mixv[j];
            f32x4 r = m * x;
            __builtin_nontemporal_store(r, &outv[j]);
        }
    }
}

extern "C" void kernel_launch(void* const* d_in, const int* in_sizes, int n_in,
                              void* d_out, int out_size, void* d_ws, size_t ws_size,
                              hipStream_t stream)
{
    const float* mlp    = (const float*)d_in[0]; // [B,N,O]
    const float* cd     = (const float*)d_in[1]; // [B,N,K,2]
    const float* sigmas = (const float*)d_in[2]; // [K]
    const float* gw     = (const float*)d_in[3]; // [B,N,K]
    const float* W      = (const float*)d_in[4]; // [K,H,O]
    float* out          = (float*)d_out;

    const int P = in_sizes[3] / KK;              // B*N = 262144

    hermite_prep_kernel<<<(V_DW + 255) / 256, 256, 0, stream>>>(W, sigmas);
    hermite_fused_kernel<<<P / PTS_BLK, 256, 0, stream>>>(mlp, cd, gw, out);
}

// Round 10
// 176.346 us; speedup vs baseline: 1.3292x; 1.3292x over previous
//
#include <hip/hip_runtime.h>

#define KK 32
#define HH 6
#define OO 31
#define EPS 1e-6f
#define PTS_BLK 256              // M=1: 256 threads, 1 pt/thread, full o per thread
#define V_DW (KK * 3 * 2 * 32)   // 6144 dwords: V[k][g(3)][h2(2)][32]

typedef float f32x16 __attribute__((ext_vector_type(16)));
typedef float f32x4  __attribute__((ext_vector_type(4)));

// Sigma-folded, group-layout, zero-padded W. 24.6 KB, rebuilt each launch by
// the prep kernel (inputs may be re-poisoned between iterations).
// Layout: V[k][g][h2][32], h = 2g + h2, col o==31 zero-padded. Group = 64
// contiguous dwords = one D=64 wait-group (4x s_load_dwordx16).
//   h=0: W0 - (W3+W5)/s2   h=1: -W1/s2 (x g*dy)   h=2: -W2/s2 (x g*dx)
//   h=3: W3/s4 (x g*dy^2)  h=4: W4/s4 (x g*dx*dy) h=5: W5/s4 (x g*dx^2)
__device__ __align__(256) float V_dev[V_DW];

__global__ void hermite_prep_kernel(const float* __restrict__ W,
                                    const float* __restrict__ sigmas)
{
    int j = blockIdx.x * 256 + threadIdx.x;
    if (j >= V_DW) return;
    int k  = j / 192;
    int r  = j - k * 192;
    int g  = r >> 6;            // group
    int r2 = r & 63;
    int h2 = r2 >> 5;
    int o  = r2 & 31;
    int h  = 2 * g + h2;
    float s  = sigmas[k];
    float s2 = s * s;
    float i2 = 1.0f / (s2 + EPS);
    float i4 = 1.0f / (s2 * s2 + EPS);
    float v = 0.0f;
    if (o < OO) {
        const float* Wk = W + k * (HH * OO);
        float w = Wk[h * OO + o];
        if (h == 0)      v = w - i2 * (Wk[3 * OO + o] + Wk[5 * OO + o]);
        else if (h <= 2) v = -i2 * w;
        else             v = i4 * w;
    }
    V_dev[j] = v;
}

// GCHUNK: one (k, h-pair) group -- 64 wave-uniform V dwords in flight under
// ONE lgkmcnt(0) via 4x s_load_dwordx16 (64 output SGPRs: inside the proven
// allocator sweet spot -- R2's 48 worked clean; R8's 96-in-x16 corrupted;
// R9's 96-in-x8 triggered ~96 v_mov SGPR-relief copies that doubled VALU
// work). Then 64 FMAs with the SGPR as the one allowed scalar operand.
// Latency model (validated R2/R3/R6/R9): duty = 4 waves * 2D/(L~600 + 2D);
// D=48 -> 55% (measured), D=64 -> 70%.
// Loads + wait in ONE asm: consumers data-depend on the asm outputs (no
// hoist hazard); SMEM returns may be OOO so only lgkmcnt(0) is safe.
#define GCHUNK(PC, DA, DB)                                                 \
    {                                                                      \
        f32x16 t0, t1, t2, t3;                                             \
        asm volatile("s_load_dwordx16 %0, %4, 0x0\n\t"                     \
                     "s_load_dwordx16 %1, %4, 0x40\n\t"                    \
                     "s_load_dwordx16 %2, %4, 0x80\n\t"                    \
                     "s_load_dwordx16 %3, %4, 0xc0\n\t"                    \
                     "s_waitcnt lgkmcnt(0)"                                \
                     : "=&s"(t0), "=&s"(t1), "=&s"(t2), "=&s"(t3)          \
                     : "s"(PC));                                           \
        _Pragma("unroll")                                                  \
        for (int o = 0; o < 16; ++o) {                                     \
            float a = acc[o];                                              \
            a = fmaf(DA, t0[o], a);                                        \
            a = fmaf(DB, t2[o], a);                                        \
            acc[o] = a;                                                    \
            float b = acc[16 + o];                                         \
            b = fmaf(DA, t1[o], b);                                        \
            b = fmaf(DB, t3[o], b);                                        \
            acc[16 + o] = b;                                               \
        }                                                                  \
    }

// 8 consecutive k's against one 64B cd sector already staged in c[16].
// Per k: 3 groups (h-pairs), 3 lgkmcnt(0) waits.
#define JBLOCK(VS, GOFF)                                                   \
    _Pragma("unroll")                                                      \
    for (int j = 0; j < 8; ++j) {                                          \
        float dx = c[2 * j], dy = c[2 * j + 1];                            \
        float g  = ga[(GOFF) + j];                                         \
        float d1 = g * dy, d2 = g * dx;                                    \
        float d3 = d1 * dy, d4 = d1 * dx, d5 = d2 * dx;                    \
        const float* pk = (VS) + j * 192;                                  \
        GCHUNK(pk,       g,  d1)                                           \
        GCHUNK(pk + 64,  d2, d3)                                           \
        GCHUNK(pk + 128, d4, d5)                                           \
    }

__global__ __launch_bounds__(256, 4) void hermite_fused_kernel(
    const float* __restrict__ mlp,     // [P, OO]
    const float* __restrict__ cd,      // [P, KK, 2]
    const float* __restrict__ gw,      // [P, KK]
    float* __restrict__ out)           // [P, OO]
{
    __shared__ float smem[PTS_BLK * OO];   // 7936 dwords = 31744 B

    const int tid = threadIdx.x;
    const int p   = blockIdx.x * PTS_BLK + tid;
    const float4* __restrict__ cdv = (const float4*)(cd + (size_t)p * (KK * 2));
    const float4* __restrict__ gwv = (const float4*)(gw + (size_t)p * KK);

    float acc[32];
#pragma unroll
    for (int o = 0; o < 32; ++o) acc[o] = 0.0f;

    const float* __restrict__ Vb = V_dev;

    // 2 outer iterations x 16 k. gw staged 16 k at a time (4 float4 = one
    // full 64B sector/lane); cd staged 8 k at a time (4 float4 = one full
    // 64B sector/lane). All register arrays statically indexed.
#pragma unroll 1
    for (int kt2 = 0; kt2 < 2; ++kt2) {
        float ga[16];
#pragma unroll
        for (int i = 0; i < 4; ++i) {
            float4 t = gwv[kt2 * 4 + i];
            ga[4 * i + 0] = t.x; ga[4 * i + 1] = t.y;
            ga[4 * i + 2] = t.z; ga[4 * i + 3] = t.w;
        }

        float c[16];
#pragma unroll
        for (int i = 0; i < 4; ++i) {
            float4 t = cdv[kt2 * 8 + i];
            c[4 * i + 0] = t.x; c[4 * i + 1] = t.y;
            c[4 * i + 2] = t.z; c[4 * i + 3] = t.w;
        }
        const float* Vs0 = Vb + (size_t)kt2 * (16 * 192);
        JBLOCK(Vs0, 0)

#pragma unroll
        for (int i = 0; i < 4; ++i) {
            float4 t = cdv[kt2 * 8 + 4 + i];
            c[4 * i + 0] = t.x; c[4 * i + 1] = t.y;
            c[4 * i + 2] = t.z; c[4 * i + 3] = t.w;
        }
        const float* Vs1 = Vs0 + 8 * 192;
        JBLOCK(Vs1, 8)
    }

    // Epilogue: transpose through LDS for coalesced float4 mlp*mix -> out.
    // Write banks (31*tid + o) mod 32 = (o - tid) mod 32: conflict-free.
#pragma unroll
    for (int o = 0; o < OO; ++o) smem[tid * OO + o] = acc[o];
    __syncthreads();

    {
        const size_t blk_dw = (size_t)blockIdx.x * (PTS_BLK * OO);
        const f32x4* __restrict__ mlpv = (const f32x4*)(mlp + blk_dw);
        f32x4* __restrict__ outv = (f32x4*)(out + blk_dw);
        const f32x4* mixv = (const f32x4*)smem;
#pragma unroll 2
        for (int j = tid; j < (PTS_BLK * OO) / 4; j += 256) {
            f32x4 m = __builtin_nontemporal_load(&mlpv[j]);
            f32x4 x = mixv[j];
            f32x4 r = m * x;
            __builtin_nontemporal_store(r, &outv[j]);
        }
    }
}

extern "C" void kernel_launch(void* const* d_in, const int* in_sizes, int n_in,
                              void* d_out, int out_size, void* d_ws, size_t ws_size,
                              hipStream_t stream)
{
    const float* mlp    = (const float*)d_in[0]; // [B,N,O]
    const float* cd     = (const float*)d_in[1]; // [B,N,K,2]
    const float* sigmas = (const float*)d_in[2]; // [K]
    const float* gw     = (const float*)d_in[3]; // [B,N,K]
    const float* W      = (const float*)d_in[4]; // [K,H,O]
    float* out          = (float*)d_out;

    const int P = in_sizes[3] / KK;              // B*N = 262144

    hermite_prep_kernel<<<(V_DW + 255) / 256, 256, 0, stream>>>(W, sigmas);
    hermite_fused_kernel<<<P / PTS_BLK, 256, 0, stream>>>(mlp, cd, gw, out);
}